// Round 19
// baseline (79.015 us; speedup 1.0000x reference)
//
#include <hip/hip_runtime.h>
#include <stdint.h>
#include <math.h>

#define N_PTS 8192
#define WPB   16
#define TPB   1024
#define NBLK  512                  // 1 round at 2 blocks/CU
#define GRIDC 64
#define NCELL (GRIDC * GRIDC)
#define CW    (9.0f / 64.0f)
#define CINV  (64.0f / 9.0f)

typedef __fp16 h2 __attribute__((ext_vector_type(2)));
typedef uint32_t u32;
typedef unsigned short u16;

__device__ __forceinline__ u32 pksub(u32 a, u32 b) {
  u32 d;
  asm("v_pk_add_f16 %0, %1, %2 neg_lo:[0,1] neg_hi:[0,1]" : "=v"(d) : "v"(a), "v"(b));
  return d;
}
__device__ __forceinline__ float dot2u(u32 a, u32 b, float c) {
#if __has_builtin(__builtin_amdgcn_fdot2)
  return __builtin_amdgcn_fdot2(__builtin_bit_cast(h2, a), __builtin_bit_cast(h2, b), c, false);
#else
  h2 x = __builtin_bit_cast(h2, a), y = __builtin_bit_cast(h2, b);
  return fmaf((float)x.x, (float)y.x, fmaf((float)x.y, (float)y.y, c));
#endif
}
__device__ __forceinline__ u32 cvtpk(float a, float b) {
  return __builtin_bit_cast(u32, __builtin_amdgcn_cvt_pkrtz(a, b));
}
__device__ __forceinline__ int cellc(float v) {
  int c = (int)floorf((v + 4.5f) * CINV);
  return c < 0 ? 0 : (c > GRIDC - 1 ? GRIDC - 1 : c);
}

// ---------------- threefry2x32 (JAX partitionable random_bits) ----------------
__device__ __forceinline__ uint32_t rotl32(uint32_t x, int r) {
  return (x << r) | (x >> (32 - r));
}
__device__ __forceinline__ uint32_t threefry_bits(uint32_t idx) {
  const uint32_t k0 = 0u, k1 = 42u;
  const uint32_t k2c = k0 ^ k1 ^ 0x1BD11BDAu;
  uint32_t x0 = 0u, x1 = idx;
  x0 += k0; x1 += k1;
  x0 += x1; x1 = rotl32(x1, 13); x1 ^= x0;
  x0 += x1; x1 = rotl32(x1, 15); x1 ^= x0;
  x0 += x1; x1 = rotl32(x1, 26); x1 ^= x0;
  x0 += x1; x1 = rotl32(x1,  6); x1 ^= x0;
  x0 += k1; x1 += k2c + 1u;
  x0 += x1; x1 = rotl32(x1, 17); x1 ^= x0;
  x0 += x1; x1 = rotl32(x1, 29); x1 ^= x0;
  x0 += x1; x1 = rotl32(x1, 16); x1 ^= x0;
  x0 += x1; x1 = rotl32(x1, 24); x1 ^= x0;
  x0 += k2c; x1 += k0 + 2u;
  x0 += x1; x1 = rotl32(x1, 13); x1 ^= x0;
  x0 += x1; x1 = rotl32(x1, 15); x1 ^= x0;
  x0 += x1; x1 = rotl32(x1, 26); x1 ^= x0;
  x0 += x1; x1 = rotl32(x1,  6); x1 ^= x0;
  x0 += k0; x1 += k1 + 3u;
  x0 += x1; x1 = rotl32(x1, 17); x1 ^= x0;
  x0 += x1; x1 = rotl32(x1, 29); x1 ^= x0;
  x0 += x1; x1 = rotl32(x1, 16); x1 ^= x0;
  x0 += x1; x1 = rotl32(x1, 24); x1 ^= x0;
  x0 += k1; x1 += k2c + 4u;
  x0 += x1; x1 = rotl32(x1, 13); x1 ^= x0;
  x0 += x1; x1 = rotl32(x1, 15); x1 ^= x0;
  x0 += x1; x1 = rotl32(x1, 26); x1 ^= x0;
  x0 += x1; x1 = rotl32(x1,  6); x1 ^= x0;
  x0 += k2c; x1 += k0 + 5u;
  return x0 ^ x1;
}
__device__ __forceinline__ float erfinv_xla(float x) {
  float w = -log1pf(-x * x);
  float p;
  if (w < 5.0f) {
    w -= 2.5f;
    p = 2.81022636e-08f;
    p = fmaf(p, w, 3.43273939e-07f);
    p = fmaf(p, w, -3.5233877e-06f);
    p = fmaf(p, w, -4.39150654e-06f);
    p = fmaf(p, w, 0.00021858087f);
    p = fmaf(p, w, -0.00125372503f);
    p = fmaf(p, w, -0.00417768164f);
    p = fmaf(p, w, 0.246640727f);
    p = fmaf(p, w, 1.50140941f);
  } else {
    w = sqrtf(w) - 3.0f;
    p = -0.000200214257f;
    p = fmaf(p, w, 0.000100950558f);
    p = fmaf(p, w, 0.00134934322f);
    p = fmaf(p, w, -0.00367342844f);
    p = fmaf(p, w, 0.00573950773f);
    p = fmaf(p, w, -0.0076224613f);
    p = fmaf(p, w, 0.00943887047f);
    p = fmaf(p, w, 1.00167406f);
    p = fmaf(p, w, 2.83297682f);
  }
  return p * x;
}
__device__ __forceinline__ float jax_noise(uint32_t idx) {
  uint32_t bits = threefry_bits(idx);
  float uf = __uint_as_float((bits >> 9) | 0x3F800000u) - 1.0f;
  const float lo_u = -0.99999994f;
  float u = fmaxf(lo_u, fmaf(uf, 2.0f, lo_u));
  return 1.4142135623730951f * erfinv_xla(u) * 0.01f;
}

// ======= K1: mega kernel — per-block in-LDS grid build + R18 compute =======
__global__ __launch_bounds__(TPB, 8) void mega_kernel(const float* __restrict__ x,
                                                      float* __restrict__ stats,
                                                      float* __restrict__ hbuf) {
  __shared__ u32 sptL[N_PTS];        // 32 KB: sorted packed pts (first 4KB = prefix scratch)
  __shared__ u32 cursS[NCELL];       // 16 KB: hist+cursor, then sidx u16[8192]
  __shared__ u16 baseS[NCELL + 2];   // 8.2 KB exclusive base
  __shared__ u16 tmpS[N_PTS];        // 16 KB: tmpidx, then iimg u16[4225]
  __shared__ double sredL[16][4];
  __shared__ float meanS[2];

  const int t = threadIdx.x;
  const int w = t >> 6;
  const int s = t & 63;

  // zero histogram target
#pragma unroll
  for (int k = 0; k < 4; ++k) cursS[k * TPB + t] = 0;

  // load own 8 points (coalesced float4), cells + packed f16 + f64 stat partials
  u32 pk[8];
  int cells[8];
  double s0 = 0, s1 = 0, q0 = 0, q1 = 0;
#pragma unroll
  for (int k = 0; k < 4; ++k) {
    float4 v = ((const float4*)x)[k * TPB + t];
    cells[2 * k]     = cellc(v.y) * GRIDC + cellc(v.x);
    cells[2 * k + 1] = cellc(v.w) * GRIDC + cellc(v.z);
    pk[2 * k]     = cvtpk(v.x, v.y);
    pk[2 * k + 1] = cvtpk(v.z, v.w);
    s0 += (double)v.x + (double)v.z;
    s1 += (double)v.y + (double)v.w;
    q0 += fma((double)v.x, (double)v.x, (double)v.z * (double)v.z);
    q1 += fma((double)v.y, (double)v.y, (double)v.w * (double)v.w);
  }
  __syncthreads();  // cursS zeroed

  // histogram (LDS atomics)
#pragma unroll
  for (int k = 0; k < 8; ++k) atomicAdd(&cursS[cells[k]], 1u);

  // stats wave-reduce (fixed order; identical in every block)
#pragma unroll
  for (int m = 1; m < 64; m <<= 1) {
    s0 += __shfl_xor(s0, m); s1 += __shfl_xor(s1, m);
    q0 += __shfl_xor(q0, m); q1 += __shfl_xor(q1, m);
  }
  if (s == 0) { sredL[w][0] = s0; sredL[w][1] = s1; sredL[w][2] = q0; sredL[w][3] = q1; }
  __syncthreads();  // histogram + sred complete

  // prefix sum over 4096 cells (scratch inside sptL; sptL not yet used for points)
  {
    u32* ssc = sptL;
    u32 c0 = cursS[t * 4], c1 = cursS[t * 4 + 1], c2 = cursS[t * 4 + 2], c3 = cursS[t * 4 + 3];
    u32 sum = c0 + c1 + c2 + c3;
    ssc[t] = sum;
    __syncthreads();
    for (int off = 1; off < 1024; off <<= 1) {
      u32 v = (t >= off) ? ssc[t - off] : 0u;
      __syncthreads();
      ssc[t] += v;
      __syncthreads();
    }
    u32 run = ssc[t] - sum;  // exclusive
    u32 b0 = run, b1 = run + c0, b2 = b1 + c1, b3 = b2 + c2;
    __syncthreads();  // all count reads done before overwrite
    baseS[t * 4] = (u16)b0; baseS[t * 4 + 1] = (u16)b1;
    baseS[t * 4 + 2] = (u16)b2; baseS[t * 4 + 3] = (u16)b3;
    cursS[t * 4] = b0; cursS[t * 4 + 1] = b1; cursS[t * 4 + 2] = b2; cursS[t * 4 + 3] = b3;
    if (t == 0) {
      baseS[NCELL] = (u16)N_PTS;
      double a0 = 0, a1 = 0, d0 = 0, d1 = 0;
      for (int k = 0; k < 16; ++k) {
        a0 += sredL[k][0]; a1 += sredL[k][1]; d0 += sredL[k][2]; d1 += sredL[k][3];
      }
      double n = (double)N_PTS, m0 = a0 / n, m1 = a1 / n;
      meanS[0] = (float)m0; meanS[1] = (float)m1;
      if (blockIdx.x == 0) {
        stats[0] = (float)m0; stats[1] = (float)m1;
        stats[2] = (float)sqrt((d0 - n * m0 * m0) / (n - 1.0));
        stats[3] = (float)sqrt((d1 - n * m1 * m1) / (n - 1.0));
      }
    }
    __syncthreads();
  }

  // placement into tmpS (LDS cursor atomics; order arbitrary, fixed by rank below)
#pragma unroll
  for (int k = 0; k < 4; ++k) {
    u32 sl0 = atomicAdd(&cursS[cells[2 * k]], 1u);
    tmpS[sl0] = (u16)(2 * (k * TPB + t));
    u32 sl1 = atomicAdd(&cursS[cells[2 * k + 1]], 1u);
    tmpS[sl1] = (u16)(2 * (k * TPB + t) + 1);
  }
  __syncthreads();  // placement done; cursS dead -> region becomes sidx

  // stable rank within cell (by orig index -> deterministic) + scatter
  u16* sidxL = (u16*)cursS;
#pragma unroll
  for (int k = 0; k < 8; ++k) {
    u32 i = (u32)(2 * ((k >> 1) * TPB + t) + (k & 1));
    int c = cells[k];
    u32 lo = baseS[c], hi = baseS[c + 1];
    u32 rk = 0;
    for (u32 j = lo; j < hi; ++j) rk += ((u32)tmpS[j] < i) ? 1u : 0u;
    u32 d = lo + rk;
    sptL[d] = pk[k];
    sidxL[d] = (u16)i;
  }
  __syncthreads();  // sptL/sidxL ready; tmpS dead -> region becomes iimg

  // integral image (u16) from baseS
  u16* iimgS = tmpS;
  if (t <= 64) {
    u32 acc = 0;
    iimgS[t] = 0;
    for (int yy = 0; yy < GRIDC; ++yy) {
      int idx = yy * GRIDC + t;
      u32 v = (idx < NCELL) ? (u32)baseS[idx] : (u32)N_PTS;
      acc += v - (u32)baseS[yy * GRIDC];
      iimgS[(yy + 1) * 65 + t] = (u16)acc;
    }
  }
  __syncthreads();

  // ======================= compute phase (R18 verbatim) =======================
  const int p = w * NBLK + blockIdx.x;  // strided row mapping
  const int orig = (int)sidxL[p];
  const float2 xg = ((const float2*)x)[orig];
  const u32 xihu = cvtpk(xg.x, xg.y);
  const int cx = cellc(xg.x), cy = cellc(xg.y);
  const float INF = 3.402823466e+38f;
  const uint4* v4 = (const uint4*)sptL;

  int r = 1;
  bool fullA = false;
  for (;;) {
    int cxl = max(cx - r, 0), cxh = min(cx + r, GRIDC - 1);
    int cyl = max(cy - r, 0), cyh = min(cy + r, GRIDC - 1);
    int c = (int)iimgS[(cyh + 1) * 65 + cxh + 1] - (int)iimgS[cyl * 65 + cxh + 1]
          - (int)iimgS[(cyh + 1) * 65 + cxl] + (int)iimgS[cyl * 65 + cxl];
    if (c >= 160) break;
    int nr = (3 * r + 1) >> 1;
    if (nr > 11) { fullA = true; break; }
    r = nr;
  }

  float d2k;
  for (;;) {
    float r0 = INF, r1 = INF, r2 = INF, r3 = INF, r4 = INF, r5 = INF;
    int cxl, cxh, cyl, cyh;
    if (fullA) { cxl = 0; cxh = GRIDC - 1; cyl = 0; cyh = GRIDC - 1; }
    else {
      cxl = max(cx - r, 0); cxh = min(cx + r, GRIDC - 1);
      cyl = max(cy - r, 0); cyh = min(cy + r, GRIDC - 1);
    }
#define INS6(d2)                      \
    r5 = fminf(fmaxf(r4, d2), r5);    \
    r4 = fminf(fmaxf(r3, d2), r4);    \
    r3 = fminf(fmaxf(r2, d2), r3);    \
    r2 = fminf(fmaxf(r1, d2), r2);    \
    r1 = fminf(fmaxf(r0, d2), r1);    \
    r0 = fminf(r0, d2);
#define DQ(qp, dd) { u32 e = pksub(xihu, qp); dd = dot2u(e, e, 0.0f); }
    if (fullA) {
      for (u32 it = 0; it < 16; ++it) {
        uint4 a = v4[it * 128 + (u32)s];
        uint4 b = v4[it * 128 + 64 + (u32)s];
        float d0, d1, d2, d3, d4, d5, d6, d7;
        DQ(a.x, d0) DQ(a.y, d1) DQ(a.z, d2) DQ(a.w, d3)
        DQ(b.x, d4) DQ(b.y, d5) DQ(b.z, d6) DQ(b.w, d7)
        INS6(d0) INS6(d1) INS6(d2) INS6(d3)
        INS6(d4) INS6(d5) INS6(d6) INS6(d7)
      }
    } else {
      u32 acc = 0;
      for (int yy = cyl; yy <= cyh; ++yy) {
        const int rowb = yy << 6;
        u32 lo = baseS[rowb + cxl];
        u32 len = (u32)baseS[rowb + cxh + 1] - lo;
        u32 k = ((u32)s - acc) & 63u;
        for (; k + 192u < len; k += 256u) {
          u32 qa = sptL[lo + k];
          u32 qb = sptL[lo + k + 64u];
          u32 qc = sptL[lo + k + 128u];
          u32 qd = sptL[lo + k + 192u];
          float da, db, dc, dd;
          DQ(qa, da) DQ(qb, db) DQ(qc, dc) DQ(qd, dd)
          INS6(da) INS6(db) INS6(dc) INS6(dd)
        }
        for (; k < len; k += 64u) {
          u32 qa = sptL[lo + k];
          float da;
          DQ(qa, da)
          INS6(da)
        }
        acc += len;
      }
    }
#undef DQ
#undef INS6
    u32 b0 = (u32)__builtin_bit_cast(u16, (__fp16)r0);
    u32 b1 = (u32)__builtin_bit_cast(u16, (__fp16)r1);
    u32 b2 = (u32)__builtin_bit_cast(u16, (__fp16)r2);
    u32 b3 = (u32)__builtin_bit_cast(u16, (__fp16)r3);
    u32 b4 = (u32)__builtin_bit_cast(u16, (__fp16)r4);
    u32 b5 = (u32)__builtin_bit_cast(u16, (__fp16)r5);
    u32 blo = 0u, bhi = 0x7C01u;
    for (int it = 0; it < 15; ++it) {
      u32 mid = (blo + bhi) >> 1;
      int c = __popcll(__ballot(b0 < mid)) + __popcll(__ballot(b1 < mid)) +
              __popcll(__ballot(b2 < mid)) + __popcll(__ballot(b3 < mid)) +
              __popcll(__ballot(b4 < mid)) + __popcll(__ballot(b5 < mid));
      bool ge = (c >= 32);
      bhi = ge ? mid : bhi;
      blo = ge ? blo : mid;
    }
    u16 v32 = (u16)(bhi - 1u);
    d2k = (float)__builtin_bit_cast(__fp16, v32);

    float d32 = sqrtf(d2k) + 1e-2f;
    float mxl = ((fullA ? 0 : max(cx - r, 0)) > 0) ? xg.x - (-4.5f + max(cx - r, 0) * CW) : 1e9f;
    // recompute bounds exactly as used in the scan
    int cxl2, cxh2, cyl2, cyh2;
    if (fullA) { cxl2 = 0; cxh2 = GRIDC - 1; cyl2 = 0; cyh2 = GRIDC - 1; }
    else {
      cxl2 = max(cx - r, 0); cxh2 = min(cx + r, GRIDC - 1);
      cyl2 = max(cy - r, 0); cyh2 = min(cy + r, GRIDC - 1);
    }
    mxl = (cxl2 > 0) ? xg.x - (-4.5f + cxl2 * CW) : 1e9f;
    float mxh = (cxh2 < GRIDC - 1) ? (-4.5f + (cxh2 + 1) * CW) - xg.x : 1e9f;
    float myl = (cyl2 > 0) ? xg.y - (-4.5f + cyl2 * CW) : 1e9f;
    float myh = (cyh2 < GRIDC - 1) ? (-4.5f + (cyh2 + 1) * CW) - xg.y : 1e9f;
    float margin = fminf(fminf(mxl, mxh), fminf(myl, myh));
    if (d32 <= margin) break;
    int nr = (3 * r + 1) >> 1;
    if (nr > 11) fullA = true; else r = nr;
  }

  const float den = fmaf(2.0f, d2k, 1e-8f);
  const float nc1 = -1.4426950408889634f / den;  // w_scaled = 2^(10 + nc1*d)
  const float dcut = 9.704f * den;               // cut at scaled weight 2^-4

  float sw0 = 0.f, swx0 = 0.f, swy0 = 0.f;
  float sw1 = 0.f, swx1 = 0.f, swy1 = 0.f;
  {
    const int bxl = cellc(xg.x - dcut), bxh = cellc(xg.x + dcut);
    const int byl = cellc(xg.y - dcut), byh = cellc(xg.y + dcut);
    const bool fullB = (byh - byl + 1 > 20);
#define WACC0(qp)                                                    \
    {                                                                \
      u32 e = pksub(xihu, qp);                                       \
      float d = __builtin_amdgcn_sqrtf(dot2u(e, e, 0.0f));           \
      float wgt = __builtin_amdgcn_exp2f(fmaf(nc1, d, 10.0f));       \
      h2 ph = __builtin_bit_cast(h2, qp);                            \
      sw0 += wgt;                                                    \
      swx0 = fmaf(wgt, (float)ph.x, swx0);                           \
      swy0 = fmaf(wgt, (float)ph.y, swy0);                           \
    }
#define WACC1(qp)                                                    \
    {                                                                \
      u32 e = pksub(xihu, qp);                                       \
      float d = __builtin_amdgcn_sqrtf(dot2u(e, e, 0.0f));           \
      float wgt = __builtin_amdgcn_exp2f(fmaf(nc1, d, 10.0f));       \
      h2 ph = __builtin_bit_cast(h2, qp);                            \
      sw1 += wgt;                                                    \
      swx1 = fmaf(wgt, (float)ph.x, swx1);                           \
      swy1 = fmaf(wgt, (float)ph.y, swy1);                           \
    }
    if (fullB) {
      for (u32 it = 0; it < 16; ++it) {
        uint4 a = v4[it * 128 + (u32)s];
        uint4 b = v4[it * 128 + 64 + (u32)s];
        WACC0(a.x) WACC1(a.y) WACC0(a.z) WACC1(a.w)
        WACC0(b.x) WACC1(b.y) WACC0(b.z) WACC1(b.w)
      }
    } else {
      u32 acc = 0;
      for (int yy = byl; yy <= byh; ++yy) {
        const int rowb = yy << 6;
        u32 lo = baseS[rowb + bxl];
        u32 len = (u32)baseS[rowb + bxh + 1] - lo;
        u32 k = ((u32)s - acc) & 63u;
        for (; k + 64u < len; k += 128u) {
          u32 qa = sptL[lo + k];
          u32 qb = sptL[lo + k + 64u];
          WACC0(qa) WACC1(qb)
        }
        if (k < len) { u32 qa = sptL[lo + k]; WACC0(qa) }
        acc += len;
      }
    }
#undef WACC0
#undef WACC1
  }
  float sw = sw0 + sw1, swx = swx0 + swx1, swy = swy0 + swy1;
#pragma unroll
  for (int m = 1; m < 64; m <<= 1) {
    sw  += __shfl_xor(sw,  m);
    swx += __shfl_xor(swx, m);
    swy += __shfl_xor(swy, m);
  }

  if (s < 2) {
    const float mean = meanS[s];
    float inv   = 1.0f / (sw + 1e-8f);               // 2^10 scaling cancels in drift
    float drift = (s == 0 ? swx : swy) * inv - mean;
    float xcv   = (s == 0 ? xg.x : xg.y) - mean;
    uint32_t idx = 2u * (uint32_t)orig + (uint32_t)s;
    hbuf[idx] = fmaf(0.5f, drift - xcv, xcv) + jax_noise(idx);
  }
}

// ======= K2: every block reduces hbuf (deterministic) + writes scaled slice =======
__global__ __launch_bounds__(256) void scalefinal_kernel(const float* __restrict__ stats,
                                                         const float* __restrict__ hbuf,
                                                         float* __restrict__ out) {
  __shared__ double red[256][4];
  __shared__ float sc[2];
  const int t = threadIdx.x;
  double s0 = 0, s1 = 0, q0 = 0, q1 = 0;
#pragma unroll
  for (int k = 0; k < 32; ++k) {
    float2 v = ((const float2*)hbuf)[t + k * 256];
    s0 += (double)v.x; s1 += (double)v.y;
    q0 += (double)v.x * (double)v.x; q1 += (double)v.y * (double)v.y;
  }
  red[t][0] = s0; red[t][1] = s1; red[t][2] = q0; red[t][3] = q1;
  __syncthreads();
  for (int st = 128; st > 0; st >>= 1) {
    if (t < st) {
      red[t][0] += red[t + st][0]; red[t][1] += red[t + st][1];
      red[t][2] += red[t + st][2]; red[t][3] += red[t + st][3];
    }
    __syncthreads();
  }
  if (t < 2) {
    double n = (double)N_PTS;
    double m = red[0][t] / n;
    double v = (red[0][2 + t] - n * m * m) / (n - 1.0);
    sc[t] = stats[2 + t] / ((float)sqrt(v) + 1e-8f);
  }
  __syncthreads();
  int i = blockIdx.x * 256 + t;
  int d = i & 1;
  out[i] = fmaf(hbuf[i], sc[d], stats[d]);
}

extern "C" void kernel_launch(void* const* d_in, const int* in_sizes, int n_in,
                              void* d_out, int out_size, void* d_ws, size_t ws_size,
                              hipStream_t stream) {
  const float* x = (const float*)d_in[0];
  float* out = (float*)d_out;
  char* W = (char*)d_ws;
  float* stats = (float*)W;              // 16 B
  float* hbuf  = (float*)(W + 64);       // 16384 f32 = 64 KB

  mega_kernel<<<NBLK, TPB, 0, stream>>>(x, stats, hbuf);
  scalefinal_kernel<<<16384 / 256, 256, 0, stream>>>(stats, hbuf, out);
}

// Round 20
// 52.280 us; speedup vs baseline: 1.5114x; 1.5114x over previous
//
#include <hip/hip_runtime.h>
#include <stdint.h>
#include <math.h>

#define N_PTS 8192
#define WPB   16
#define TPB   (WPB * 64)           // 1024
#define NBLK  (N_PTS / WPB)        // 512 blocks (1 round at 2 blocks/CU)
#define GRIDC 64
#define NCELL (GRIDC * GRIDC)
#define CW    (9.0f / 64.0f)
#define CINV  (64.0f / 9.0f)

typedef __fp16 h2 __attribute__((ext_vector_type(2)));
typedef uint32_t u32;

__device__ __forceinline__ u32 pksub(u32 a, u32 b) {
  u32 d;
  asm("v_pk_add_f16 %0, %1, %2 neg_lo:[0,1] neg_hi:[0,1]" : "=v"(d) : "v"(a), "v"(b));
  return d;
}
__device__ __forceinline__ float dot2u(u32 a, u32 b, float c) {
#if __has_builtin(__builtin_amdgcn_fdot2)
  return __builtin_amdgcn_fdot2(__builtin_bit_cast(h2, a), __builtin_bit_cast(h2, b), c, false);
#else
  h2 x = __builtin_bit_cast(h2, a), y = __builtin_bit_cast(h2, b);
  return fmaf((float)x.x, (float)y.x, fmaf((float)x.y, (float)y.y, c));
#endif
}
__device__ __forceinline__ u32 cvtpk(float a, float b) {
  return __builtin_bit_cast(u32, __builtin_amdgcn_cvt_pkrtz(a, b));
}
__device__ __forceinline__ int cellc(float v) {
  int c = (int)floorf((v + 4.5f) * CINV);
  return c < 0 ? 0 : (c > GRIDC - 1 ? GRIDC - 1 : c);
}

// ---------------- threefry2x32 (JAX partitionable random_bits) ----------------
__device__ __forceinline__ uint32_t rotl32(uint32_t x, int r) {
  return (x << r) | (x >> (32 - r));
}
__device__ __forceinline__ uint32_t threefry_bits(uint32_t idx) {
  const uint32_t k0 = 0u, k1 = 42u;
  const uint32_t k2c = k0 ^ k1 ^ 0x1BD11BDAu;
  uint32_t x0 = 0u, x1 = idx;
  x0 += k0; x1 += k1;
  x0 += x1; x1 = rotl32(x1, 13); x1 ^= x0;
  x0 += x1; x1 = rotl32(x1, 15); x1 ^= x0;
  x0 += x1; x1 = rotl32(x1, 26); x1 ^= x0;
  x0 += x1; x1 = rotl32(x1,  6); x1 ^= x0;
  x0 += k1; x1 += k2c + 1u;
  x0 += x1; x1 = rotl32(x1, 17); x1 ^= x0;
  x0 += x1; x1 = rotl32(x1, 29); x1 ^= x0;
  x0 += x1; x1 = rotl32(x1, 16); x1 ^= x0;
  x0 += x1; x1 = rotl32(x1, 24); x1 ^= x0;
  x0 += k2c; x1 += k0 + 2u;
  x0 += x1; x1 = rotl32(x1, 13); x1 ^= x0;
  x0 += x1; x1 = rotl32(x1, 15); x1 ^= x0;
  x0 += x1; x1 = rotl32(x1, 26); x1 ^= x0;
  x0 += x1; x1 = rotl32(x1,  6); x1 ^= x0;
  x0 += k0; x1 += k1 + 3u;
  x0 += x1; x1 = rotl32(x1, 17); x1 ^= x0;
  x0 += x1; x1 = rotl32(x1, 29); x1 ^= x0;
  x0 += x1; x1 = rotl32(x1, 16); x1 ^= x0;
  x0 += x1; x1 = rotl32(x1, 24); x1 ^= x0;
  x0 += k1; x1 += k2c + 4u;
  x0 += x1; x1 = rotl32(x1, 13); x1 ^= x0;
  x0 += x1; x1 = rotl32(x1, 15); x1 ^= x0;
  x0 += x1; x1 = rotl32(x1, 26); x1 ^= x0;
  x0 += x1; x1 = rotl32(x1,  6); x1 ^= x0;
  x0 += k2c; x1 += k0 + 5u;
  return x0 ^ x1;
}
__device__ __forceinline__ float erfinv_xla(float x) {
  float w = -log1pf(-x * x);
  float p;
  if (w < 5.0f) {
    w -= 2.5f;
    p = 2.81022636e-08f;
    p = fmaf(p, w, 3.43273939e-07f);
    p = fmaf(p, w, -3.5233877e-06f);
    p = fmaf(p, w, -4.39150654e-06f);
    p = fmaf(p, w, 0.00021858087f);
    p = fmaf(p, w, -0.00125372503f);
    p = fmaf(p, w, -0.00417768164f);
    p = fmaf(p, w, 0.246640727f);
    p = fmaf(p, w, 1.50140941f);
  } else {
    w = sqrtf(w) - 3.0f;
    p = -0.000200214257f;
    p = fmaf(p, w, 0.000100950558f);
    p = fmaf(p, w, 0.00134934322f);
    p = fmaf(p, w, -0.00367342844f);
    p = fmaf(p, w, 0.00573950773f);
    p = fmaf(p, w, -0.0076224613f);
    p = fmaf(p, w, 0.00943887047f);
    p = fmaf(p, w, 1.00167406f);
    p = fmaf(p, w, 2.83297682f);
  }
  return p * x;
}
__device__ __forceinline__ float jax_noise(uint32_t idx) {
  uint32_t bits = threefry_bits(idx);
  float uf = __uint_as_float((bits >> 9) | 0x3F800000u) - 1.0f;
  const float lo_u = -0.99999994f;
  float u = fmaxf(lo_u, fmaf(uf, 2.0f, lo_u));
  return 1.4142135623730951f * erfinv_xla(u) * 0.01f;
}

// ======= K1: single-block LDS-only build: hist + 3-barrier prefix + iimg + stats =======
__global__ __launch_bounds__(1024) void build1_kernel(const float* __restrict__ x,
                                                      float* __restrict__ stats,
                                                      u32* __restrict__ base,
                                                      u32* __restrict__ cursor,
                                                      u32* __restrict__ iimg) {
  __shared__ u32 baseL[NCELL];
  __shared__ u32 wtot[16];
  __shared__ double sred[16][4];
  const int t = threadIdx.x;
  const int wid = t >> 6;
  const int lane = t & 63;

#pragma unroll
  for (int k = 0; k < 4; ++k) baseL[t * 4 + k] = 0;
  __syncthreads();

  double s0 = 0, s1 = 0, q0 = 0, q1 = 0;
#pragma unroll
  for (int k = 0; k < 8; ++k) {
    float2 p = ((const float2*)x)[t * 8 + k];
    int cell = cellc(p.y) * GRIDC + cellc(p.x);
    atomicAdd(&baseL[cell], 1u);
    s0 += (double)p.x; s1 += (double)p.y;
    q0 += (double)p.x * (double)p.x; q1 += (double)p.y * (double)p.y;
  }
#pragma unroll
  for (int m = 1; m < 64; m <<= 1) {
    s0 += __shfl_xor(s0, m); s1 += __shfl_xor(s1, m);
    q0 += __shfl_xor(q0, m); q1 += __shfl_xor(q1, m);
  }
  if (lane == 0) {
    sred[wid][0] = s0; sred[wid][1] = s1; sred[wid][2] = q0; sred[wid][3] = q1;
  }
  __syncthreads();  // histogram + sred complete

  // ---- 3-barrier hierarchical exclusive prefix over 4096 cells ----
  u32 c0 = baseL[t * 4], c1 = baseL[t * 4 + 1], c2 = baseL[t * 4 + 2], c3 = baseL[t * 4 + 3];
  u32 sum = c0 + c1 + c2 + c3;
  // wave-inclusive scan of per-thread sums
  u32 inc = sum;
#pragma unroll
  for (int m = 1; m < 64; m <<= 1) {
    u32 v = __shfl_up(inc, m);
    if (lane >= m) inc += v;
  }
  if (lane == 63) wtot[wid] = inc;
  __syncthreads();
  if (t == 0) {  // serial exclusive scan of 16 wave totals
    u32 running = 0;
#pragma unroll
    for (int k = 0; k < 16; ++k) { u32 v = wtot[k]; wtot[k] = running; running += v; }
  }
  __syncthreads();
  u32 run = (inc - sum) + wtot[wid];  // exclusive base for this thread's 4 cells
  u32 b0 = run, b1 = run + c0, b2 = b1 + c1, b3 = b2 + c2;
  __syncthreads();  // all histogram reads complete before overwrite
  baseL[t * 4] = b0; baseL[t * 4 + 1] = b1; baseL[t * 4 + 2] = b2; baseL[t * 4 + 3] = b3;
  base[t * 4] = b0;   base[t * 4 + 1] = b1;   base[t * 4 + 2] = b2;   base[t * 4 + 3] = b3;
  cursor[t * 4] = b0; cursor[t * 4 + 1] = b1; cursor[t * 4 + 2] = b2; cursor[t * 4 + 3] = b3;
  if (t == 1023) base[NCELL] = N_PTS;
  if (t == 0) {
    double a0 = 0, a1 = 0, d0 = 0, d1 = 0;
    for (int k = 0; k < 16; ++k) {
      a0 += sred[k][0]; a1 += sred[k][1]; d0 += sred[k][2]; d1 += sred[k][3];
    }
    double n = (double)N_PTS, m0 = a0 / n, m1 = a1 / n;
    stats[0] = (float)m0; stats[1] = (float)m1;
    stats[2] = (float)sqrt((d0 - n * m0 * m0) / (n - 1.0));
    stats[3] = (float)sqrt((d1 - n * m1 * m1) / (n - 1.0));
  }
  __syncthreads();

  if (t <= 64) {
    u32 acc = 0;
    iimg[t] = 0;
    for (int yy = 0; yy < GRIDC; ++yy) {
      int idx = yy * GRIDC + t;
      u32 v = (idx < NCELL) ? baseL[idx] : (u32)N_PTS;
      acc += v - baseL[yy * GRIDC];
      iimg[(yy + 1) * 65 + t] = acc;
    }
  }
}

// ======= K2: place (parallel global scatter) =======
__global__ __launch_bounds__(256) void place_kernel(const float* __restrict__ x,
                                                    u32* __restrict__ cursor,
                                                    u32* __restrict__ tmp_pt,
                                                    u32* __restrict__ tmp_ci) {
  int i = blockIdx.x * 256 + threadIdx.x;
  float2 p = ((const float2*)x)[i];
  int cell = cellc(p.y) * GRIDC + cellc(p.x);
  u32 slot = atomicAdd(&cursor[cell], 1u);
  tmp_pt[slot] = cvtpk(p.x, p.y);
  tmp_ci[slot] = ((u32)cell << 13) | (u32)i;
}

// ======= K3: stable rank within cell (parallel global gather) =======
__global__ __launch_bounds__(256) void rank_kernel(const u32* __restrict__ base,
                                                   const u32* __restrict__ tmp_pt,
                                                   const u32* __restrict__ tmp_ci,
                                                   u32* __restrict__ spt,
                                                   unsigned short* __restrict__ sidx) {
  int s = blockIdx.x * 256 + threadIdx.x;
  u32 v = tmp_ci[s];
  u32 cell = v >> 13, i = v & 8191u;
  u32 lo = base[cell], hi = base[cell + 1];
  u32 rank = 0;
  for (u32 j = lo; j < hi; ++j) rank += ((tmp_ci[j] & 8191u) < i) ? 1u : 0u;
  u32 d = lo + rank;
  spt[d] = tmp_pt[s];
  sidx[d] = (unsigned short)i;
}

// ======= K4: main — banded scans, all tables LDS-resident, wide ILP =======
__global__ __launch_bounds__(TPB, 2) void main_kernel(const float* __restrict__ x,
                                                      const float* __restrict__ stats,
                                                      const u32* __restrict__ base,
                                                      const u32* __restrict__ iimg,
                                                      const u32* __restrict__ spt,
                                                      const unsigned short* __restrict__ sidx,
                                                      float* __restrict__ hbuf) {
  __shared__ u32 sptL[N_PTS];       // 32 KB
  __shared__ u32 baseL[NCELL + 1];  // 16.4 KB
  __shared__ u32 iimgL[65 * 65];    // 16.9 KB
  const int t = threadIdx.x;
  const int w = t >> 6;
  const int s = t & 63;

#pragma unroll
  for (int k = 0; k < 2; ++k)
    ((uint4*)sptL)[k * TPB + t] = ((const uint4*)spt)[k * TPB + t];
#pragma unroll
  for (int k = 0; k < 4; ++k) baseL[k * TPB + t] = base[k * TPB + t];
  if (t == 0) baseL[NCELL] = N_PTS;
#pragma unroll
  for (int k = 0; k < 5; ++k) {
    int i = k * TPB + t;
    if (i < 65 * 65) iimgL[i] = iimg[i];
  }
  __syncthreads();

  // strided assignment: spatially-clustered straggler rows spread across blocks
  const int p = w * NBLK + blockIdx.x;
  const int orig = (int)sidx[p];
  const float2 xg = ((const float2*)x)[orig];
  const u32 xihu = cvtpk(xg.x, xg.y);
  const int cx = cellc(xg.x), cy = cellc(xg.y);
  const float INF = 3.402823466e+38f;
  const uint4* v4 = (const uint4*)sptL;

  // pre-size r from integral image (LDS)
  int r = 1;
  bool fullA = false;
  for (;;) {
    int cxl = max(cx - r, 0), cxh = min(cx + r, GRIDC - 1);
    int cyl = max(cy - r, 0), cyh = min(cy + r, GRIDC - 1);
    u32 c = iimgL[(cyh + 1) * 65 + cxh + 1] - iimgL[cyl * 65 + cxh + 1]
          - iimgL[(cyh + 1) * 65 + cxl] + iimgL[cyl * 65 + cxl];
    if (c >= 160u) break;
    int nr = (3 * r + 1) >> 1;
    if (nr > 11) { fullA = true; break; }
    r = nr;
  }

  // phase A: scan + exact rank-32 + verify
  float d2k;
  for (;;) {
    float r0 = INF, r1 = INF, r2 = INF, r3 = INF, r4 = INF, r5 = INF;
    int cxl, cxh, cyl, cyh;
    if (fullA) { cxl = 0; cxh = GRIDC - 1; cyl = 0; cyh = GRIDC - 1; }
    else {
      cxl = max(cx - r, 0); cxh = min(cx + r, GRIDC - 1);
      cyl = max(cy - r, 0); cyh = min(cy + r, GRIDC - 1);
    }
#define INS6(d2)                      \
    r5 = fminf(fmaxf(r4, d2), r5);    \
    r4 = fminf(fmaxf(r3, d2), r4);    \
    r3 = fminf(fmaxf(r2, d2), r3);    \
    r2 = fminf(fmaxf(r1, d2), r2);    \
    r1 = fminf(fmaxf(r0, d2), r1);    \
    r0 = fminf(r0, d2);
#define DQ(qp, dd) { u32 e = pksub(xihu, qp); dd = dot2u(e, e, 0.0f); }
    if (fullA) {
      for (u32 it = 0; it < 16; ++it) {
        uint4 a = v4[it * 128 + (u32)s];
        uint4 b = v4[it * 128 + 64 + (u32)s];
        float d0, d1, d2, d3, d4, d5, d6, d7;
        DQ(a.x, d0) DQ(a.y, d1) DQ(a.z, d2) DQ(a.w, d3)
        DQ(b.x, d4) DQ(b.y, d5) DQ(b.z, d6) DQ(b.w, d7)
        INS6(d0) INS6(d1) INS6(d2) INS6(d3)
        INS6(d4) INS6(d5) INS6(d6) INS6(d7)
      }
    } else {
      u32 acc = 0;  // continuous stream striding across bands
      for (int yy = cyl; yy <= cyh; ++yy) {
        const int rowb = yy << 6;
        u32 lo = baseL[rowb + cxl];
        u32 len = baseL[rowb + cxh + 1] - lo;
        u32 k = ((u32)s - acc) & 63u;
        for (; k + 192u < len; k += 256u) {  // 4 independent LDS loads
          u32 qa = sptL[lo + k];
          u32 qb = sptL[lo + k + 64u];
          u32 qc = sptL[lo + k + 128u];
          u32 qd = sptL[lo + k + 192u];
          float da, db, dc, dd;
          DQ(qa, da) DQ(qb, db) DQ(qc, dc) DQ(qd, dd)
          INS6(da) INS6(db) INS6(dc) INS6(dd)
        }
        for (; k < len; k += 64u) {
          u32 qa = sptL[lo + k];
          float da;
          DQ(qa, da)
          INS6(da)
        }
        acc += len;
      }
    }
#undef DQ
#undef INS6
    u32 b0 = (u32)__builtin_bit_cast(unsigned short, (__fp16)r0);
    u32 b1 = (u32)__builtin_bit_cast(unsigned short, (__fp16)r1);
    u32 b2 = (u32)__builtin_bit_cast(unsigned short, (__fp16)r2);
    u32 b3 = (u32)__builtin_bit_cast(unsigned short, (__fp16)r3);
    u32 b4 = (u32)__builtin_bit_cast(unsigned short, (__fp16)r4);
    u32 b5 = (u32)__builtin_bit_cast(unsigned short, (__fp16)r5);
    u32 blo = 0u, bhi = 0x7C01u;
    for (int it = 0; it < 15; ++it) {
      u32 mid = (blo + bhi) >> 1;
      int c = __popcll(__ballot(b0 < mid)) + __popcll(__ballot(b1 < mid)) +
              __popcll(__ballot(b2 < mid)) + __popcll(__ballot(b3 < mid)) +
              __popcll(__ballot(b4 < mid)) + __popcll(__ballot(b5 < mid));
      bool ge = (c >= 32);
      bhi = ge ? mid : bhi;
      blo = ge ? blo : mid;
    }
    unsigned short v32 = (unsigned short)(bhi - 1u);
    d2k = (float)__builtin_bit_cast(__fp16, v32);

    float d32 = sqrtf(d2k) + 1e-2f;
    float mxl = (cxl > 0) ? xg.x - (-4.5f + cxl * CW) : 1e9f;
    float mxh = (cxh < GRIDC - 1) ? (-4.5f + (cxh + 1) * CW) - xg.x : 1e9f;
    float myl = (cyl > 0) ? xg.y - (-4.5f + cyl * CW) : 1e9f;
    float myh = (cyh < GRIDC - 1) ? (-4.5f + (cyh + 1) * CW) - xg.y : 1e9f;
    float margin = fminf(fminf(mxl, mxh), fminf(myl, myh));
    if (d32 <= margin) break;
    int nr = (3 * r + 1) >> 1;
    if (nr > 11) fullA = true; else r = nr;
  }

  const float den = fmaf(2.0f, d2k, 1e-8f);
  const float nc1 = -1.4426950408889634f / den;  // w_scaled = 2^(10 + nc1*d)
  const float dcut = 9.704f * den;               // cut at scaled weight 2^-4

  // phase B: weight sums — dual accumulator chains (deterministic fixed order)
  float sw0 = 0.f, swx0 = 0.f, swy0 = 0.f;
  float sw1 = 0.f, swx1 = 0.f, swy1 = 0.f;
  {
    const int bxl = cellc(xg.x - dcut), bxh = cellc(xg.x + dcut);
    const int byl = cellc(xg.y - dcut), byh = cellc(xg.y + dcut);
    const bool fullB = (byh - byl + 1 > 20);
#define WACC0(qp)                                                    \
    {                                                                \
      u32 e = pksub(xihu, qp);                                       \
      float d = __builtin_amdgcn_sqrtf(dot2u(e, e, 0.0f));           \
      float wgt = __builtin_amdgcn_exp2f(fmaf(nc1, d, 10.0f));       \
      h2 ph = __builtin_bit_cast(h2, qp);                            \
      sw0 += wgt;                                                    \
      swx0 = fmaf(wgt, (float)ph.x, swx0);                           \
      swy0 = fmaf(wgt, (float)ph.y, swy0);                           \
    }
#define WACC1(qp)                                                    \
    {                                                                \
      u32 e = pksub(xihu, qp);                                       \
      float d = __builtin_amdgcn_sqrtf(dot2u(e, e, 0.0f));           \
      float wgt = __builtin_amdgcn_exp2f(fmaf(nc1, d, 10.0f));       \
      h2 ph = __builtin_bit_cast(h2, qp);                            \
      sw1 += wgt;                                                    \
      swx1 = fmaf(wgt, (float)ph.x, swx1);                           \
      swy1 = fmaf(wgt, (float)ph.y, swy1);                           \
    }
    if (fullB) {
      for (u32 it = 0; it < 16; ++it) {
        uint4 a = v4[it * 128 + (u32)s];
        uint4 b = v4[it * 128 + 64 + (u32)s];
        WACC0(a.x) WACC1(a.y) WACC0(a.z) WACC1(a.w)
        WACC0(b.x) WACC1(b.y) WACC0(b.z) WACC1(b.w)
      }
    } else {
      u32 acc = 0;
      for (int yy = byl; yy <= byh; ++yy) {
        const int rowb = yy << 6;
        u32 lo = baseL[rowb + bxl];
        u32 len = baseL[rowb + bxh + 1] - lo;
        u32 k = ((u32)s - acc) & 63u;
        for (; k + 64u < len; k += 128u) {
          u32 qa = sptL[lo + k];
          u32 qb = sptL[lo + k + 64u];
          WACC0(qa) WACC1(qb)
        }
        if (k < len) { u32 qa = sptL[lo + k]; WACC0(qa) }
        acc += len;
      }
    }
#undef WACC0
#undef WACC1
  }
  float sw = sw0 + sw1, swx = swx0 + swx1, swy = swy0 + swy1;
#pragma unroll
  for (int m = 1; m < 64; m <<= 1) {
    sw  += __shfl_xor(sw,  m);
    swx += __shfl_xor(swx, m);
    swy += __shfl_xor(swy, m);
  }

  if (s < 2) {
    const float mean = stats[s];
    float inv   = 1.0f / (sw + 1e-8f);               // 2^10 scaling cancels in drift
    float drift = (s == 0 ? swx : swy) * inv - mean;
    float xcv   = (s == 0 ? xg.x : xg.y) - mean;
    uint32_t idx = 2u * (uint32_t)orig + (uint32_t)s;
    hbuf[idx] = fmaf(0.5f, drift - xcv, xcv) + jax_noise(idx);
  }
}

// ======= K5: every block reduces hbuf (deterministic) + writes scaled slice =======
__global__ __launch_bounds__(256) void scalefinal_kernel(const float* __restrict__ stats,
                                                         const float* __restrict__ hbuf,
                                                         float* __restrict__ out) {
  __shared__ double red[256][4];
  __shared__ float sc[2];
  const int t = threadIdx.x;
  double s0 = 0, s1 = 0, q0 = 0, q1 = 0;
#pragma unroll
  for (int k = 0; k < 32; ++k) {
    float2 v = ((const float2*)hbuf)[t + k * 256];
    s0 += (double)v.x; s1 += (double)v.y;
    q0 += (double)v.x * (double)v.x; q1 += (double)v.y * (double)v.y;
  }
  red[t][0] = s0; red[t][1] = s1; red[t][2] = q0; red[t][3] = q1;
  __syncthreads();
  for (int st = 128; st > 0; st >>= 1) {
    if (t < st) {
      red[t][0] += red[t + st][0]; red[t][1] += red[t + st][1];
      red[t][2] += red[t + st][2]; red[t][3] += red[t + st][3];
    }
    __syncthreads();
  }
  if (t < 2) {
    double n = (double)N_PTS;
    double m = red[0][t] / n;
    double v = (red[0][2 + t] - n * m * m) / (n - 1.0);
    sc[t] = stats[2 + t] / ((float)sqrt(v) + 1e-8f);
  }
  __syncthreads();
  int i = blockIdx.x * 256 + t;
  int d = i & 1;
  out[i] = fmaf(hbuf[i], sc[d], stats[d]);
}

extern "C" void kernel_launch(void* const* d_in, const int* in_sizes, int n_in,
                              void* d_out, int out_size, void* d_ws, size_t ws_size,
                              hipStream_t stream) {
  const float* x = (const float*)d_in[0];
  float* out = (float*)d_out;
  char* W = (char*)d_ws;
  float* stats = (float*)W;                               // 16 B
  u32* base   = (u32*)(W + 128);                          // 4097 u32
  u32* cursor = (u32*)(W + 16640);                        // 4096 u32
  u32* iimg   = (u32*)(W + 33152);                        // 65*65 u32
  unsigned short* sidx = (unsigned short*)(W + 50176);    // 8192 u16
  u32* tmp_pt = (u32*)(W + 66560);                        // 8192 u32
  u32* tmp_ci = (u32*)(W + 99328);                        // 8192 u32
  u32* spt    = (u32*)(W + 132096);                       // 8192 u32; ends 164864
  float* hbuf = (float*)(W + 66560);                      // overlays tmp (dead after rank)

  build1_kernel<<<1, 1024, 0, stream>>>(x, stats, base, cursor, iimg);
  place_kernel<<<N_PTS / 256, 256, 0, stream>>>(x, cursor, tmp_pt, tmp_ci);
  rank_kernel<<<N_PTS / 256, 256, 0, stream>>>(base, tmp_pt, tmp_ci, spt, sidx);
  main_kernel<<<NBLK, TPB, 0, stream>>>(x, stats, base, iimg, spt, sidx, hbuf);
  scalefinal_kernel<<<16384 / 256, 256, 0, stream>>>(stats, hbuf, out);
}